// Round 1
// baseline (497.687 us; speedup 1.0000x reference)
//
#include <hip/hip_runtime.h>
#include <math.h>

// Problem constants (b=2, f=8, c=64, h=256, w=256)
#define BF    16          // b*f
#define CH    64          // channels
#define HW    65536       // h*w

// Native clang vector type
typedef float vfloat4 __attribute__((ext_vector_type(4)));

// ---------------------------------------------------------------------------
// Kernel 1: ksum[bf*CH + c] = sum_{xy} nbr[bf, c, xy]
// grid = BF*CH = 1024 blocks (one per channel, all resident: 4 blocks/CU),
// 256 threads. Each block streams one contiguous 256 KiB channel with plain
// float4 loads (the pattern that measures 6.29 TB/s on this chip), reduces
// once, writes the FINAL channel sum (no SPLIT partial pass).
// ---------------------------------------------------------------------------
__global__ __launch_bounds__(256) void ksum_kernel(
    const float* __restrict__ nbr, float* __restrict__ ksum) {
    const int ch  = blockIdx.x;          // 0 .. BF*CH-1
    const int tid = threadIdx.x;

    const vfloat4* base = (const vfloat4*)(nbr + (size_t)ch * HW);
    float sum = 0.f;
#pragma unroll 8
    for (int k = 0; k < HW / (256 * 4); ++k) {   // 64 iters, 8 loads in flight
        vfloat4 v = base[tid + k * 256];
        sum += (v.x + v.y) + (v.z + v.w);
    }
    // wave-64 shuffle reduction
#pragma unroll
    for (int off = 32; off > 0; off >>= 1)
        sum += __shfl_down(sum, off, 64);

    __shared__ float red[4];
    const int lane = tid & 63, wv = tid >> 6;
    if (lane == 0) red[wv] = sum;
    __syncthreads();
    if (tid == 0)
        ksum[ch] = (red[0] + red[1]) + (red[2] + red[3]);
}

// ---------------------------------------------------------------------------
// Kernel 2: weight[bf, xy] = sigmoid( sum_c ref[bf, c, xy] * ksum[bf, c] )
// grid = BF * (HW / 1024) = 1024 blocks (all resident), 256 threads;
// 4 pixels (float4) per thread. 2-channel unroll x8 => 16 loads in flight.
// Plain (cached) loads; NT store only for the 4 MiB output.
// ---------------------------------------------------------------------------
__global__ __launch_bounds__(256) void weight_kernel(
    const float* __restrict__ ref, const float* __restrict__ ksum,
    float* __restrict__ out) {
    const int blocksPerBF = HW / (256 * 4);      // 64
    const int bf      = blockIdx.x / blocksPerBF;
    const int pix_blk = blockIdx.x % blocksPerBF;
    const int tid     = threadIdx.x;

    __shared__ float ks[CH];
    if (tid < CH)
        ks[tid] = ksum[(size_t)bf * CH + tid];
    __syncthreads();

    const size_t xy0 = (size_t)pix_blk * 1024 + (size_t)tid * 4;
    const float* refbase = ref + (size_t)bf * CH * HW + xy0;

    vfloat4 acc0 = {0.f, 0.f, 0.f, 0.f};
    vfloat4 acc1 = {0.f, 0.f, 0.f, 0.f};
#pragma unroll 8
    for (int c = 0; c < CH; c += 2) {
        vfloat4 r0 = *(const vfloat4*)(refbase + (size_t)c * HW);
        vfloat4 r1 = *(const vfloat4*)(refbase + (size_t)(c + 1) * HW);
        const float k0 = ks[c], k1 = ks[c + 1];
        acc0.x = fmaf(r0.x, k0, acc0.x);
        acc0.y = fmaf(r0.y, k0, acc0.y);
        acc0.z = fmaf(r0.z, k0, acc0.z);
        acc0.w = fmaf(r0.w, k0, acc0.w);
        acc1.x = fmaf(r1.x, k1, acc1.x);
        acc1.y = fmaf(r1.y, k1, acc1.y);
        acc1.z = fmaf(r1.z, k1, acc1.z);
        acc1.w = fmaf(r1.w, k1, acc1.w);
    }

    vfloat4 o;
    o.x = 1.f / (1.f + __expf(-(acc0.x + acc1.x)));
    o.y = 1.f / (1.f + __expf(-(acc0.y + acc1.y)));
    o.z = 1.f / (1.f + __expf(-(acc0.z + acc1.z)));
    o.w = 1.f / (1.f + __expf(-(acc0.w + acc1.w)));

    __builtin_nontemporal_store(o, (vfloat4*)(out + (size_t)bf * HW + xy0));
}

// ---------------------------------------------------------------------------
extern "C" void kernel_launch(void* const* d_in, const int* in_sizes, int n_in,
                              void* d_out, int out_size, void* d_ws, size_t ws_size,
                              hipStream_t stream) {
    const float* nbr = (const float*)d_in[0];
    const float* ref = (const float*)d_in[1];
    float* out       = (float*)d_out;
    float* ksum      = (float*)d_ws;   // BF*CH floats = 4 KB

    ksum_kernel<<<BF * CH, 256, 0, stream>>>(nbr, ksum);
    weight_kernel<<<BF * (HW / 1024), 256, 0, stream>>>(ref, ksum, out);
}

// Round 2
// 474.886 us; speedup vs baseline: 1.0480x; 1.0480x over previous
//
#include <hip/hip_runtime.h>
#include <math.h>

// Problem constants (b=2, f=8, c=64, h=256, w=256)
#define BF    16          // b*f
#define CH    64          // channels
#define HW    65536       // h*w

// Native clang vector type — required by __builtin_nontemporal_load/store
typedef float vfloat4 __attribute__((ext_vector_type(4)));

// ---------------------------------------------------------------------------
// Kernel 1: ksum[bf*CH + c] = sum_{xy} nbr[bf, c, xy]
// grid = BF*CH = 1024 blocks (one per channel, all resident: 4 blocks/CU),
// 256 threads. Each block streams one contiguous 256 KiB channel with
// NONTEMPORAL float4 loads (no L2 allocation -> no dirty-line evictions of
// the harness's 1 GiB poison fill), reduces once, writes the final sum.
// ---------------------------------------------------------------------------
__global__ __launch_bounds__(256) void ksum_kernel(
    const float* __restrict__ nbr, float* __restrict__ ksum) {
    const int ch  = blockIdx.x;          // 0 .. BF*CH-1
    const int tid = threadIdx.x;

    const vfloat4* base = (const vfloat4*)(nbr + (size_t)ch * HW);
    float sum = 0.f;
#pragma unroll 8
    for (int k = 0; k < HW / (256 * 4); ++k) {   // 64 iters, 8 loads in flight
        vfloat4 v = __builtin_nontemporal_load(&base[tid + k * 256]);
        sum += (v.x + v.y) + (v.z + v.w);
    }
    // wave-64 shuffle reduction
#pragma unroll
    for (int off = 32; off > 0; off >>= 1)
        sum += __shfl_down(sum, off, 64);

    __shared__ float red[4];
    const int lane = tid & 63, wv = tid >> 6;
    if (lane == 0) red[wv] = sum;
    __syncthreads();
    if (tid == 0)
        ksum[ch] = (red[0] + red[1]) + (red[2] + red[3]);
}

// ---------------------------------------------------------------------------
// Kernel 2: weight[bf, xy] = sigmoid( sum_c ref[bf, c, xy] * ksum[bf, c] )
// grid = BF * (HW / 1024) = 1024 blocks (all resident), 256 threads;
// 4 pixels (float4) per thread. 2-channel unroll x8 => 16 NT loads in flight.
// ---------------------------------------------------------------------------
__global__ __launch_bounds__(256) void weight_kernel(
    const float* __restrict__ ref, const float* __restrict__ ksum,
    float* __restrict__ out) {
    const int blocksPerBF = HW / (256 * 4);      // 64
    const int bf      = blockIdx.x / blocksPerBF;
    const int pix_blk = blockIdx.x % blocksPerBF;
    const int tid     = threadIdx.x;

    __shared__ float ks[CH];
    if (tid < CH)
        ks[tid] = ksum[(size_t)bf * CH + tid];
    __syncthreads();

    const size_t xy0 = (size_t)pix_blk * 1024 + (size_t)tid * 4;
    const float* refbase = ref + (size_t)bf * CH * HW + xy0;

    vfloat4 acc0 = {0.f, 0.f, 0.f, 0.f};
    vfloat4 acc1 = {0.f, 0.f, 0.f, 0.f};
#pragma unroll 8
    for (int c = 0; c < CH; c += 2) {
        vfloat4 r0 = __builtin_nontemporal_load(
            (const vfloat4*)(refbase + (size_t)c * HW));
        vfloat4 r1 = __builtin_nontemporal_load(
            (const vfloat4*)(refbase + (size_t)(c + 1) * HW));
        const float k0 = ks[c], k1 = ks[c + 1];
        acc0.x = fmaf(r0.x, k0, acc0.x);
        acc0.y = fmaf(r0.y, k0, acc0.y);
        acc0.z = fmaf(r0.z, k0, acc0.z);
        acc0.w = fmaf(r0.w, k0, acc0.w);
        acc1.x = fmaf(r1.x, k1, acc1.x);
        acc1.y = fmaf(r1.y, k1, acc1.y);
        acc1.z = fmaf(r1.z, k1, acc1.z);
        acc1.w = fmaf(r1.w, k1, acc1.w);
    }

    vfloat4 o;
    o.x = 1.f / (1.f + __expf(-(acc0.x + acc1.x)));
    o.y = 1.f / (1.f + __expf(-(acc0.y + acc1.y)));
    o.z = 1.f / (1.f + __expf(-(acc0.z + acc1.z)));
    o.w = 1.f / (1.f + __expf(-(acc0.w + acc1.w)));

    __builtin_nontemporal_store(o, (vfloat4*)(out + (size_t)bf * HW + xy0));
}

// ---------------------------------------------------------------------------
extern "C" void kernel_launch(void* const* d_in, const int* in_sizes, int n_in,
                              void* d_out, int out_size, void* d_ws, size_t ws_size,
                              hipStream_t stream) {
    const float* nbr = (const float*)d_in[0];
    const float* ref = (const float*)d_in[1];
    float* out       = (float*)d_out;
    float* ksum      = (float*)d_ws;   // BF*CH floats = 4 KB

    ksum_kernel<<<BF * CH, 256, 0, stream>>>(nbr, ksum);
    weight_kernel<<<BF * (HW / 1024), 256, 0, stream>>>(ref, ksum, out);
}